// Round 1
// baseline (371.762 us; speedup 1.0000x reference)
//
#include <hip/hip_runtime.h>
#include <hip/hip_bf16.h>
#include <math.h>

#define BB 4
#define DD 60
#define SS 512
#define FF 158
#define CC 64
#define HH 128
#define FC 222      // F + C
#define G3 384      // 3H
#define NN 2048     // B*S
#define BDN 240     // B*D

typedef _Float16 f16x8 __attribute__((ext_vector_type(8)));
typedef float f32x4 __attribute__((ext_vector_type(4)));

__device__ __forceinline__ float sigmoidf_(float x){ return 1.0f/(1.0f+__expf(-x)); }
// tanh(x) = 1 - 2/(e^{2x}+1): 5 VALU ops, saturates correctly at +/-inf
__device__ __forceinline__ float tanh_fast_(float x){
    float e = __expf(2.0f*x);
    return 1.0f - 2.0f/(e + 1.0f);
}

// ---- prep: wf16 (384x224) xproj, wqkv (192x160) qkv, whh16 (384x128) gru -------------
__global__ void prep_kernel(const float* __restrict__ w_ih,
                            const float* __restrict__ wq, const float* __restrict__ wk,
                            const float* __restrict__ wv, const float* __restrict__ w_hh,
                            _Float16* __restrict__ wf16, _Float16* __restrict__ wqkv,
                            _Float16* __restrict__ whh16){
    int idx = blockIdx.x*256 + threadIdx.x;
    if (idx < 384*224){
        int n = idx / 224, k = idx % 224;
        wf16[idx] = (k < FC) ? (_Float16)w_ih[n*FC + k] : (_Float16)0.0f;
    } else if (idx < 384*224 + 192*160){
        int i2 = idx - 384*224;
        int n = i2 / 160, k = i2 % 160;
        float v = 0.0f;
        if (k < FF){
            if (n < 64)       v = wq[k*CC + n];
            else if (n < 128) v = wk[k*CC + (n-64)];
            else              v = wv[k*CC + (n-128)];
        }
        wqkv[i2] = (_Float16)v;
    } else {
        int i3 = idx - (384*224 + 192*160);
        if (i3 < 384*128)
            whh16[i3] = (_Float16)w_hh[i3];
    }
}

// ---------------- QKV via f16 MFMA: 64 rows/block, 256 thr (4 waves) ------------------
__global__ __launch_bounds__(256) void qkv_kernel(const float* __restrict__ x,
                           const _Float16* __restrict__ wqkv,
                           const float* __restrict__ bq, const float* __restrict__ bk,
                           const float* __restrict__ bv,
                           _Float16* __restrict__ Qh, _Float16* __restrict__ Kh,
                           float* __restrict__ V){
    __shared__ _Float16 xa[5][64][40];   // fragment layout, 25.6 KB
    int tid  = threadIdx.x;
    int lane = tid & 63, wv = tid >> 6;
    int col  = lane & 15, quad = lane >> 4;
    int row0 = blockIdx.x * 64;

    f16x8 bfr[3][5];
    #pragma unroll
    for (int nt = 0; nt < 3; ++nt){
        int n = wv*48 + nt*16 + col;
        #pragma unroll
        for (int kq = 0; kq < 5; ++kq)
            bfr[nt][kq] = *(const f16x8*)&wqkv[n*160 + kq*32 + quad*8];
    }

    for (int i = tid; i < 64*160; i += 256){
        int r = i / 160, k = i % 160;
        float v = (k < FF) ? x[(size_t)(row0 + r)*FF + k] : 0.0f;
        xa[k >> 5][r][k & 31] = (_Float16)v;
    }
    __syncthreads();

    float bias[3];
    #pragma unroll
    for (int nt = 0; nt < 3; ++nt){
        int n = wv*48 + nt*16 + col;
        bias[nt] = (n < 64) ? bq[n] : (n < 128 ? bk[n-64] : bv[n-128]);
    }

    #pragma unroll 1
    for (int mt = 0; mt < 4; ++mt){
        f16x8 a[5];
        #pragma unroll
        for (int kq = 0; kq < 5; ++kq)
            a[kq] = *(const f16x8*)&xa[kq][mt*16 + col][quad*8];
        #pragma unroll
        for (int nt = 0; nt < 3; ++nt){
            f32x4 c = {0.0f, 0.0f, 0.0f, 0.0f};
            #pragma unroll
            for (int kq = 0; kq < 5; ++kq)
                c = __builtin_amdgcn_mfma_f32_16x16x32_f16(a[kq], bfr[nt][kq], c, 0, 0, 0);
            int n = wv*48 + nt*16 + col;
            #pragma unroll
            for (int reg = 0; reg < 4; ++reg){
                int row = row0 + mt*16 + quad*4 + reg;
                float val = c[reg] + bias[nt];
                if (n < 64)       Qh[(size_t)row*CC + n]       = (_Float16)val;
                else if (n < 128) Kh[(size_t)row*CC + (n-64)]  = (_Float16)val;
                else              V [(size_t)row*CC + (n-128)] = val;
            }
        }
    }
}

// ---------------- attention + fused market: one block per bd --------------------------
__global__ __launch_bounds__(512) void attn_kernel(const _Float16* __restrict__ Qh,
                                                   const _Float16* __restrict__ Kh,
                                                   const int* __restrict__ mask,
                                                   const float* __restrict__ V,
                                                   float* __restrict__ market){
    __shared__ _Float16 kf[2][512][32];   // 64 KB
    __shared__ float w_sh[512];
    __shared__ float mk_lds[512];

    int tid  = threadIdx.x;
    int bd   = blockIdx.x;
    int lane = tid & 63, wv = tid >> 6;
    int col  = lane & 15, quad = lane >> 4;

    const _Float16* qb = Qh + (size_t)(bd*SS)*CC;
    const _Float16* kb = Kh + (size_t)(bd*SS)*CC;

    {
        int t = tid;
        w_sh[t] = 0.0f;
        mk_lds[t] = (mask[bd*SS + t] != 0) ? 1.0f : 0.0f;
    }
    for (int i = tid; i < 4096; i += 512){
        int t = i >> 3, ch = i & 7;
        *(f16x8*)&kf[ch >> 2][t][(ch & 3)*8] = *(const f16x8*)&kb[t*CC + ch*8];
    }

    f16x8 a0[4], a1[4];
    #pragma unroll
    for (int af = 0; af < 4; ++af){
        int row = wv*64 + af*16 + col;
        a0[af] = *(const f16x8*)&qb[row*CC + quad*8];
        a1[af] = *(const f16x8*)&qb[row*CC + 32 + quad*8];
    }
    __syncthreads();

    // ---- pass 0: row sums l ----
    float lacc[4][4] = {{0,0,0,0},{0,0,0,0},{0,0,0,0},{0,0,0,0}};
    #pragma unroll 2
    for (int kt = 0; kt < 32; ++kt){
        f16x8 b0 = *(const f16x8*)&kf[0][kt*16 + col][quad*8];
        f16x8 b1 = *(const f16x8*)&kf[1][kt*16 + col][quad*8];
        float mkv = mk_lds[kt*16 + col];
        #pragma unroll
        for (int af = 0; af < 4; ++af){
            f32x4 c = {0.0f, 0.0f, 0.0f, 0.0f};
            c = __builtin_amdgcn_mfma_f32_16x16x32_f16(a0[af], b0, c, 0, 0, 0);
            c = __builtin_amdgcn_mfma_f32_16x16x32_f16(a1[af], b1, c, 0, 0, 0);
            #pragma unroll
            for (int reg = 0; reg < 4; ++reg)
                lacc[af][reg] += __expf(c[reg]*0.125f) * mkv;
        }
    }
    float crv[4][4];
    #pragma unroll
    for (int af = 0; af < 4; ++af){
        #pragma unroll
        for (int reg = 0; reg < 4; ++reg){
            float l = lacc[af][reg];
            l += __shfl_xor(l, 1, 64);
            l += __shfl_xor(l, 2, 64);
            l += __shfl_xor(l, 4, 64);
            l += __shfl_xor(l, 8, 64);
            int row = wv*64 + af*16 + quad*4 + reg;
            crv[af][reg] = mk_lds[row] / l;
        }
    }

    // ---- pass 1: accumulate W columns ----
    #pragma unroll 2
    for (int kt = 0; kt < 32; ++kt){
        f16x8 b0 = *(const f16x8*)&kf[0][kt*16 + col][quad*8];
        f16x8 b1 = *(const f16x8*)&kf[1][kt*16 + col][quad*8];
        float s = 0.0f;
        #pragma unroll
        for (int af = 0; af < 4; ++af){
            f32x4 c = {0.0f, 0.0f, 0.0f, 0.0f};
            c = __builtin_amdgcn_mfma_f32_16x16x32_f16(a0[af], b0, c, 0, 0, 0);
            c = __builtin_amdgcn_mfma_f32_16x16x32_f16(a1[af], b1, c, 0, 0, 0);
            #pragma unroll
            for (int reg = 0; reg < 4; ++reg)
                s = fmaf(__expf(c[reg]*0.125f), crv[af][reg], s);
        }
        s += __shfl_xor(s, 16, 64);
        s += __shfl_xor(s, 32, 64);
        if (quad == 0)
            atomicAdd(&w_sh[kt*16 + col], s);
    }
    __syncthreads();   // w_sh final; kf reads complete -> reuse kf as scratch

    // ---- fused market ----
    float* msum = (float*)kf;
    {
        int c = tid & 63, grp = tid >> 6;
        const float* vb = V + (size_t)(bd*SS)*CC;
        float acc = 0.0f;
        int t0 = grp*64;
        #pragma unroll 4
        for (int t = t0; t < t0 + 64; ++t)
            acc = fmaf(w_sh[t]*mk_lds[t], vb[(size_t)t*CC + c], acc);
        msum[grp*64 + c] = acc;
    }
    __syncthreads();
    if (tid < 64){
        float s = 0.0f;
        #pragma unroll
        for (int g = 0; g < 8; ++g) s += msum[g*64 + tid];
        float cnt = 0.0f;
        #pragma unroll
        for (int j = 0; j < 8; ++j) cnt += mk_lds[tid + 64*j];
        #pragma unroll
        for (int o = 1; o < 64; o <<= 1) cnt += __shfl_xor(cnt, o, 64);
        market[bd*CC + tid] = s / fmaxf(cnt, 1.0f);
    }
}

// ---------------- fused LN + x_proj f16 MFMA GEMM -------------------------------------
__global__ __launch_bounds__(512, 2) void xproj_kernel(const float* __restrict__ x,
                             const float* __restrict__ market,
                             const float* __restrict__ ln_g, const float* __restrict__ ln_b,
                             const _Float16* __restrict__ wf16, const float* __restrict__ b_ih,
                             _Float16* __restrict__ XP){
    __shared__ _Float16 aug[7][64][32];   // 28 KB
    int tid  = threadIdx.x;
    int lane = tid & 63, wv = tid >> 6;
    int col  = lane & 15, quad = lane >> 4;
    int row0 = blockIdx.x * 64;

    f16x8 bfr[3][7];
    #pragma unroll
    for (int nt = 0; nt < 3; ++nt){
        int n = wv*48 + nt*16 + col;
        #pragma unroll
        for (int kq = 0; kq < 7; ++kq)
            bfr[nt][kq] = *(const f16x8*)&wf16[n*224 + kq*32 + quad*8];
    }

    {
        int wrow = wv*8 + (lane >> 3);
        int g    = lane & 7;
        int row  = row0 + wrow;
        int d = row / NN, n = row % NN;
        int b = n >> 9, s = n & 511;
        const float* xr = &x[((size_t)((b*DD + d)*SS) + s)*FF];
        const float* mr = &market[(b*DD + d)*CC];
        float v[28];
        float sum = 0.0f, sq = 0.0f;
        #pragma unroll
        for (int j = 0; j < 28; ++j){
            int f = g + 8*j;
            float vv = 0.0f;
            if (f < FF) vv = xr[f];
            else if (f < FC) vv = mr[f - FF];
            v[j] = vv;
            sum += vv; sq += vv*vv;
        }
        sum += __shfl_xor(sum,1,64); sq += __shfl_xor(sq,1,64);
        sum += __shfl_xor(sum,2,64); sq += __shfl_xor(sq,2,64);
        sum += __shfl_xor(sum,4,64); sq += __shfl_xor(sq,4,64);
        float mu   = sum * (1.0f/222.0f);
        float var  = sq * (1.0f/222.0f) - mu*mu;
        float rstd = rsqrtf(var + 1e-5f);
        #pragma unroll
        for (int j = 0; j < 28; ++j){
            int f = g + 8*j;
            float val = (f < FC) ? ((v[j]-mu)*rstd*ln_g[f] + ln_b[f]) : 0.0f;
            aug[f>>5][wrow][f&31] = (_Float16)val;
        }
    }
    __syncthreads();

    float bias[3];
    #pragma unroll
    for (int nt = 0; nt < 3; ++nt) bias[nt] = b_ih[wv*48 + nt*16 + col];
    #pragma unroll 1
    for (int mt = 0; mt < 4; ++mt){
        f16x8 a[7];
        #pragma unroll
        for (int kq = 0; kq < 7; ++kq)
            a[kq] = *(const f16x8*)&aug[kq][mt*16 + col][quad*8];
        #pragma unroll
        for (int nt = 0; nt < 3; ++nt){
            f32x4 c = {0.0f, 0.0f, 0.0f, 0.0f};
            #pragma unroll
            for (int kq = 0; kq < 7; ++kq)
                c = __builtin_amdgcn_mfma_f32_16x16x32_f16(a[kq], bfr[nt][kq], c, 0, 0, 0);
            int nn = wv*48 + nt*16 + col;
            #pragma unroll
            for (int reg = 0; reg < 4; ++reg){
                int m = quad*4 + reg;
                XP[(size_t)(row0 + mt*16 + m)*G3 + nn] = (_Float16)(c[reg] + bias[nt]);
            }
        }
    }
}

// ---------------- persistent GRU v2: 16 seqs/block, in-register gates -----------------
// 128 blocks x 512 thr (8 waves), 16 seqs/block -> MFMA M=16 fully used (was 4/16).
// Wave w owns h-cols [w*16, w*16+16) for all 3 gates: 12 MFMAs/step/wave.
// C layout (col=lane&15, row=quad*4+reg) => each lane holds r/z/n pre-activations for
// 4 real (seq,col) pairs IN REGISTERS -> no hp_sh LDS round-trip.
// XP consumed via 12 scalar f16 loads/thread/step, depth-2 register prefetch
// (3 rotating buffers, unroll-6 so all buffer indices are static).
#define XLOAD(dst, base_) do{                                                   \
    _Pragma("unroll") for (int rg_ = 0; rg_ < 4; ++rg_)                         \
    _Pragma("unroll") for (int g_ = 0; g_ < 3; ++g_)                            \
        dst[rg_][g_] = (base_)[rg_*G3 + g_*HH];                                 \
}while(0)

#define GRU_STEP(PRD, PWR, XC, XPF, DOPF) do{                                   \
    if (DOPF) { XLOAD(XPF, xp_d + 2*DSTR); }                                    \
    f16x8 a_[4];                                                                \
    _Pragma("unroll") for (int kq = 0; kq < 4; ++kq)                            \
        a_[kq] = *(const f16x8*)&hfrag[PRD][kq][col][quad*8];                   \
    f32x4 c0 = {0,0,0,0}, c1 = {0,0,0,0}, c2 = {0,0,0,0};                       \
    _Pragma("unroll") for (int kq = 0; kq < 4; ++kq)                            \
        c0 = __builtin_amdgcn_mfma_f32_16x16x32_f16(a_[kq], bfr[0][kq], c0, 0,0,0); \
    _Pragma("unroll") for (int kq = 0; kq < 4; ++kq)                            \
        c1 = __builtin_amdgcn_mfma_f32_16x16x32_f16(a_[kq], bfr[1][kq], c1, 0,0,0); \
    _Pragma("unroll") for (int kq = 0; kq < 4; ++kq)                            \
        c2 = __builtin_amdgcn_mfma_f32_16x16x32_f16(a_[kq], bfr[2][kq], c2, 0,0,0); \
    _Pragma("unroll") for (int rg = 0; rg < 4; ++rg){                           \
        float r_ = sigmoidf_((float)XC[rg][0] + c0[rg] + bh0);                  \
        float z_ = sigmoidf_((float)XC[rg][1] + c1[rg] + bh1);                  \
        float n_ = tanh_fast_((float)XC[rg][2] + r_*(c2[rg] + bh2));            \
        float h_ = n_ + z_*(hcur[rg] - n_);                                     \
        hcur[rg] = h_;                                                          \
        hfrag[PWR][w >> 1][quad*4 + rg][(w & 1)*16 + col] = (_Float16)h_;       \
    }                                                                           \
    xp_d += DSTR;                                                               \
    __syncthreads();                                                            \
}while(0)

__global__ __launch_bounds__(512) void gru_kernel(const _Float16* __restrict__ XP,
                                                  const _Float16* __restrict__ whh16,
                                                  const float* __restrict__ b_hh,
                                                  const float* __restrict__ w1, const float* __restrict__ b1,
                                                  const float* __restrict__ w2, const float* __restrict__ b2,
                                                  float* __restrict__ out){
    __shared__ _Float16 hfrag[2][4][16][32];  // 8 KB, MFMA-A fragment layout, dbuf
    __shared__ float h_sh[16][132];           // final h for head (padded)

    const int tid  = threadIdx.x;
    const int lane = tid & 63, w = tid >> 6;      // 8 waves
    const int col  = lane & 15, quad = lane >> 4;
    const int row0 = blockIdx.x * 16;             // 16 seqs/block

    // zero h buffer 0 (h0 = 0)
    for (int i = tid; i < 4*16*32; i += 512)
        ((_Float16*)hfrag)[i] = (_Float16)0.0f;

    // W_hh B-fragments: n = g*128 + w*16 + col, k = kq*32 + quad*8 + j
    f16x8 bfr[3][4];
    #pragma unroll
    for (int g = 0; g < 3; ++g){
        #pragma unroll
        for (int kq = 0; kq < 4; ++kq)
            bfr[g][kq] = *(const f16x8*)&whh16[(size_t)(g*HH + w*16 + col)*HH + kq*32 + quad*8];
    }

    const float bh0 = b_hh[0*HH + w*16 + col];
    const float bh1 = b_hh[1*HH + w*16 + col];
    const float bh2 = b_hh[2*HH + w*16 + col];

    const size_t DSTR = (size_t)NN * G3;
    // thread's 12 XP values per step: seq = row0+quad*4+rg, col g*128 + w*16 + col
    const _Float16* xp_d = XP + (size_t)(row0 + quad*4)*G3 + (w*16 + col);

    _Float16 xA[4][3], xB[4][3], xC[4][3];
    XLOAD(xA, xp_d);            // d = 0
    XLOAD(xB, xp_d + DSTR);     // d = 1

    float hcur[4] = {0.0f, 0.0f, 0.0f, 0.0f};
    __syncthreads();

    #pragma unroll 1
    for (int ch = 0; ch < 10; ++ch){
        const int pf = (ch < 9);          // last chunk: d+2 would be >= 60
        GRU_STEP(0, 1, xA, xC, 1);
        GRU_STEP(1, 0, xB, xA, 1);
        GRU_STEP(0, 1, xC, xB, 1);
        GRU_STEP(1, 0, xA, xC, 1);
        GRU_STEP(0, 1, xB, xA, pf);
        GRU_STEP(1, 0, xC, xB, pf);
    }

    #pragma unroll
    for (int rg = 0; rg < 4; ++rg)
        h_sh[quad*4 + rg][w*16 + col] = hcur[rg];
    __syncthreads();

    // ---- output head: 512 thr -> 8 rows in parallel, 2 passes ----
    {
        int c2 = tid & 63;
        int rb = tid >> 6;
        #pragma unroll
        for (int rr = 0; rr < 2; ++rr){
            int r = rb + rr*8;
            float acc = 0.0f;
            #pragma unroll 8
            for (int k = 0; k < 128; ++k)
                acc = fmaf(h_sh[r][k], w1[k*64 + c2], acc);
            float hid = fmaxf(acc + b1[c2], 0.0f);
            float o = hid * w2[c2];
            #pragma unroll
            for (int off = 1; off < 64; off <<= 1) o += __shfl_xor(o, off, 64);
            if (c2 == 0) out[row0 + r] = o + b2[0];
        }
    }
}

extern "C" void kernel_launch(void* const* d_in, const int* in_sizes, int n_in,
                              void* d_out, int out_size, void* d_ws, size_t ws_size,
                              hipStream_t stream) {
    const float* x    = (const float*)d_in[0];
    const int*   mask = (const int*)d_in[1];
    const float* wq   = (const float*)d_in[2];
    const float* bq   = (const float*)d_in[3];
    const float* wk   = (const float*)d_in[4];
    const float* bk   = (const float*)d_in[5];
    const float* wv   = (const float*)d_in[6];
    const float* bv   = (const float*)d_in[7];
    const float* ln_g = (const float*)d_in[8];
    const float* ln_b = (const float*)d_in[9];
    const float* w_ih = (const float*)d_in[10];
    const float* w_hh = (const float*)d_in[11];
    const float* b_ih = (const float*)d_in[12];
    const float* b_hh = (const float*)d_in[13];
    const float* w1   = (const float*)d_in[14];
    const float* b1   = (const float*)d_in[15];
    const float* w2   = (const float*)d_in[16];
    const float* b2   = (const float*)d_in[17];

    float* ws = (float*)d_ws;
    // phase 1 (f32 index units):
    _Float16* Qh  = (_Float16*)ws;                    // f16 [0, 3,932,160)
    _Float16* Kh  = (_Float16*)(ws + 3932160);        // f16 [3,932,160, 7,864,320)
    float*    V   = ws + 7864320;                     // f32 [7,864,320, 15,728,640)
    // phase 2: XP aliases the dead Q/K/V region
    _Float16* XP  = (_Float16*)ws;                    // f16 [0, 23,592,960)
    float* market = ws + 23592960;                    //    15,360 f32
    _Float16* wf16 = (_Float16*)(ws + 23608320);      //    86,016 f16
    _Float16* wqkv = (_Float16*)(ws + 23651328);      //    30,720 f16
    _Float16* whh16= (_Float16*)(ws + 23666688);      //    49,152 f16
    // total ~94.8 MB

    prep_kernel<<<648, 256, 0, stream>>>(w_ih, wq, wk, wv, w_hh, wf16, wqkv, whh16);
    qkv_kernel<<<1920, 256, 0, stream>>>(x, wqkv, bq, bk, bv, Qh, Kh, V);
    attn_kernel<<<240, 512, 0, stream>>>(Qh, Kh, mask, V, market);
    xproj_kernel<<<1920, 512, 0, stream>>>(x, market, ln_g, ln_b, wf16, b_ih, XP);
    gru_kernel<<<128, 512, 0, stream>>>(XP, whh16, b_hh, w1, b1, w2, b2, (float*)d_out);
}